// Round 17
// baseline (1748.683 us; speedup 1.0000x reference)
//
#include <hip/hip_runtime.h>
#include <hip/hip_fp16.h>
#include <cstddef>

using half_t = __half;
typedef __attribute__((ext_vector_type(8))) _Float16 f16x8;
typedef __attribute__((ext_vector_type(4))) float f32x4;

#define T_SEQ 512
#define B_SZ  128
#define H_SZ  200
#define D_EMB 50
#define K0P   64    // layer-0 K padded (50 -> 64)
#define K_TAGS 25
#define HA_S 232   // hA row stride (halfs)
#define GL2_S 808  // gl row stride per b (halfs)
#define PB   2     // persist b-tile rows (empirical optimum, R7 U-curve)

// Gate-interleaved weight-row permutation: n' = j*4 + gate (was n = gate*200 + j).

__device__ __forceinline__ float sigf(float x) {
  return __builtin_amdgcn_rcpf(1.f + __expf(-x));   // NaN-free at +-inf
}
__device__ __forceinline__ float tanf_(float x) {
  return 1.f - 2.f * __builtin_amdgcn_rcpf(__expf(2.f * x) + 1.f);  // NaN-free
}

// x0 strided K0P with zero pad: x0[(t*128+b)*64 + d]; bsum fused (R9).
__global__ __launch_bounds__(256) void embed_kernel(const int* __restrict__ x,
                                                    const float* __restrict__ emb,
                                                    half_t* __restrict__ x0,
                                                    const float* __restrict__ b0,
                                                    const float* __restrict__ b1,
                                                    float* __restrict__ bsum) {
  int idx = blockIdx.x * 256 + threadIdx.x;
  if (idx < 3200) {
    const float* src = (idx < 1600) ? b0 : b1;
    int Lbase = (idx < 1600) ? 0 : 1600;
    int j0 = (idx < 1600) ? idx : (idx - 1600);
    int dir = j0 / 800, n = j0 % 800;        // n = g*200 + j (original order)
    int g = n / 200, jj = n % 200;
    float v = src[dir * 1600 + n] + src[dir * 1600 + 800 + n];
    bsum[Lbase + dir * 800 + jj * 4 + g] = v;
  }
  if (idx >= T_SEQ * B_SZ * K0P) return;
  int d  = idx & (K0P - 1);
  int tb = idx >> 6;
  int b  = tb % B_SZ;
  int t  = tb / B_SZ;
  float v = 0.f;
  if (d < D_EMB) {
    int tok = x[b * T_SEQ + t];
    v = emb[(size_t)tok * D_EMB + d];
  }
  x0[idx] = __float2half(v);
}

// generic fp32->fp16 pad-convert (no permutation): dst[r][k]
__global__ __launch_bounds__(256) void conv_pad_kernel(const float* __restrict__ src,
                                                       half_t* __restrict__ dst,
                                                       int Rsrc, int Ksrc, int Kdst, int n) {
  int i = blockIdx.x * 256 + threadIdx.x;
  if (i >= n) return;
  int k = i % Kdst, r = i / Kdst;
  float v = (r < Rsrc && k < Ksrc) ? src[(size_t)r * Ksrc + k] : 0.f;
  dst[i] = __float2half(v);
}

// Wih -> fp16, rows permuted to n' = j*4+g. src [2][800][Ksrc], dst [2][800][Kdst]
__global__ __launch_bounds__(256) void conv_pad_perm_kernel(const float* __restrict__ src,
                                                            half_t* __restrict__ dst,
                                                            int Ksrc, int Kdst, int n) {
  int i = blockIdx.x * 256 + threadIdx.x;
  if (i >= n) return;
  int k   = i % Kdst;
  int np  = (i / Kdst) % 800;
  int dir = i / (Kdst * 800);
  int g = np & 3, j = np >> 2;
  float v = (k < Ksrc) ? src[((size_t)dir * 800 + g * 200 + j) * Ksrc + k] : 0.f;
  dst[i] = __float2half(v);
}

// Whh -> MFMA A-operand fragments, fp16, PERMUTED rows; both layers (R9).
__global__ __launch_bounds__(256) void conv_wfrag_kernel(const float* __restrict__ whh0,
                                                         const float* __restrict__ whh1,
                                                         half_t* __restrict__ dst0,
                                                         half_t* __restrict__ dst1) {
  int idx = blockIdx.x * 256 + threadIdx.x;
  if (idx >= 2 * 50 * 7 * 512) return;
  const float* whh = blockIdx.y ? whh1 : whh0;
  half_t* dst = blockIdx.y ? dst1 : dst0;
  int i8   = idx & 7;
  int lane = (idx >> 3) & 63;
  int kt   = (idx >> 9) % 7;
  int tmp  = (idx >> 9) / 7;      // d*50 + tt
  int tt   = tmp % 50, d = tmp / 50;
  int np = tt * 16 + (lane & 15);
  int g = np & 3, j = np >> 2;
  int k = kt * 32 + (lane >> 4) * 8 + i8;
  float v = (k < H_SZ) ? whh[((size_t)d * 800 + g * 200 + j) * H_SZ + k] : 0.f;
  dst[idx] = __float2half(v);
}

// Standalone xw GEMM (first chunk only), 128x128 tile (R8/R11 verified).
// Grid (7, 2*C), 256 thr. chunk layout (fp16): [sc][dir][b][np=800]
__global__ __launch_bounds__(256) void xw_mfma2_kernel(const half_t* __restrict__ A,
                                                       const half_t* __restrict__ Wh,
                                                       const float* __restrict__ bsumL,
                                                       half_t* __restrict__ chunk,
                                                       int K, int C, int q) {
  __shared__ __align__(16) unsigned short As[128][40];
  __shared__ __align__(16) unsigned short Bs[128][40];
  const int tid = threadIdx.x;
  const int w = tid >> 6, lane = tid & 63;
  const int col = lane & 15, quad = lane >> 4;
  const int dirTq = blockIdx.y;
  const int dir = dirTq / C;
  const int tq  = dirTq - dir * C;
  const int t = dir ? (T_SEQ - 1 - q * C - tq) : (q * C + tq);
  const int n0 = blockIdx.x * 128;
  const size_t Arow0 = (size_t)t * B_SZ;
  f32x4 acc[2][8];
#pragma unroll
  for (int mi = 0; mi < 2; ++mi)
#pragma unroll
    for (int c = 0; c < 8; ++c) acc[mi][c] = (f32x4){0.f, 0.f, 0.f, 0.f};

  const int nkb = (K + 31) / 32;
  const int rA = tid >> 1, sA = (tid & 1) * 2;
  const int nB = n0 + rA;

  uint4 va0, va1, vb0, vb1;
  {
    int k = sA * 8;
    va0 = (k < K) ? *(const uint4*)&A[(Arow0 + rA) * K + k] : make_uint4(0, 0, 0, 0);
    va1 = (k + 8 < K) ? *(const uint4*)&A[(Arow0 + rA) * K + k + 8] : make_uint4(0, 0, 0, 0);
    vb0 = (k < K && nB < 800) ? *(const uint4*)&Wh[((size_t)dir * 800 + nB) * K + k]
                              : make_uint4(0, 0, 0, 0);
    vb1 = (k + 8 < K && nB < 800) ? *(const uint4*)&Wh[((size_t)dir * 800 + nB) * K + k + 8]
                                  : make_uint4(0, 0, 0, 0);
  }

  for (int kb = 0; kb < nkb; ++kb) {
    *(uint4*)&As[rA][sA * 8] = va0;
    *(uint4*)&As[rA][sA * 8 + 8] = va1;
    *(uint4*)&Bs[rA][sA * 8] = vb0;
    *(uint4*)&Bs[rA][sA * 8 + 8] = vb1;
    uint4 na0 = make_uint4(0, 0, 0, 0), na1 = na0, nb0 = na0, nb1 = na0;
    if (kb + 1 < nkb) {
      int k0n = (kb + 1) * 32;
      int k = k0n + sA * 8;
      if (k < K)     na0 = *(const uint4*)&A[(Arow0 + rA) * K + k];
      if (k + 8 < K) na1 = *(const uint4*)&A[(Arow0 + rA) * K + k + 8];
      if (k < K && nB < 800)     nb0 = *(const uint4*)&Wh[((size_t)dir * 800 + nB) * K + k];
      if (k + 8 < K && nB < 800) nb1 = *(const uint4*)&Wh[((size_t)dir * 800 + nB) * K + k + 8];
    }
    asm volatile("s_waitcnt lgkmcnt(0)" ::: "memory");
    __builtin_amdgcn_s_barrier();
    __builtin_amdgcn_sched_barrier(0);
    f16x8 af0 = *(const f16x8*)&As[w * 32 + col][quad * 8];
    f16x8 af1 = *(const f16x8*)&As[w * 32 + 16 + col][quad * 8];
#pragma unroll
    for (int c = 0; c < 8; ++c) {
      f16x8 bf = *(const f16x8*)&Bs[c * 16 + col][quad * 8];
      acc[0][c] = __builtin_amdgcn_mfma_f32_16x16x32_f16(af0, bf, acc[0][c], 0, 0, 0);
      acc[1][c] = __builtin_amdgcn_mfma_f32_16x16x32_f16(af1, bf, acc[1][c], 0, 0, 0);
    }
    asm volatile("s_waitcnt lgkmcnt(0)" ::: "memory");
    __builtin_amdgcn_s_barrier();
    __builtin_amdgcn_sched_barrier(0);
    va0 = na0; va1 = na1; vb0 = nb0; vb1 = nb1;
  }

#pragma unroll
  for (int c = 0; c < 8; ++c) {
    int np = n0 + c * 16 + col;
    if (np < 800) {
      float bia = bsumL[dir * 800 + np];
#pragma unroll
      for (int mi = 0; mi < 2; ++mi)
#pragma unroll
        for (int r = 0; r < 4; ++r) {
          int brow = w * 32 + mi * 16 + quad * 4 + r;
          chunk[(((size_t)tq * 2 + dir) * B_SZ + brow) * 800 + np] =
              __float2half(acc[mi][c][r] + bia);
        }
    }
  }
}

// R13 FUSED kernel: blocks 0..127 = persist5 recurrence; blocks 128.. = xw GEMM
// for the NEXT chunk. R17: rec-role MFMA u-chains split into two alternating
// partial accumulators (chain depth 7 -> 4, independent MFMAs interleave) --
// attacks the ~1400cyc serialized-MFMA phase (VGPR=112 showed the allocator
// minimized registers instead of interleaving the 7 dependent chains).
__global__ __launch_bounds__(512)
__attribute__((amdgpu_waves_per_eu(2, 2)))
void persist9_kernel(
    const half_t* __restrict__ chunk,     // rec: [sc][d][b][np] fp16
    const half_t* __restrict__ wfragG,    // [d][50][7][64][8] fp16 (permuted)
    float* __restrict__ hslab,            // [d][128][200] fp32
    float* __restrict__ cslab,            // [d][128][200] fp32
    half_t* __restrict__ hbuf,            // [t][128][400] fp16
    int q, int C,
    int doXw,
    const half_t* __restrict__ Ax,        // xw: activation input
    const half_t* __restrict__ Whx,       // xw: weights (permuted rows)
    const float* __restrict__ bsx,        // xw: bias
    half_t* __restrict__ chx,             // xw: output chunk (other buffer)
    int Kx, int qx) {
  const int tid = threadIdx.x;

  __shared__ __align__(16) unsigned short wlds[50 * 2 * 512];  // 102400 B
  __shared__ __align__(16) unsigned short gl[PB * GL2_S];      // 3232 B
  __shared__ __align__(16) unsigned short hA[16 * HA_S];       // 7424 B
  __shared__ __align__(16) unsigned short Axs[2][128][40];     // 20480 B
  __shared__ __align__(16) unsigned short Bxs[2][128][40];     // 20480 B

  if (blockIdx.x >= 128) {
    // ---------------- xw role (next chunk) ----------------
    const int xb = blockIdx.x - 128;
    const int n0 = (xb % 7) * 128;
    const int pair = xb / 7;             // [0, C)
    const int half = tid >> 8;           // wave-uniform (256 | wave bounds)
    const int stid = tid & 255;
    const int dir = half, tq = pair;
    const int t = dir ? (T_SEQ - 1 - qx * C - tq) : (qx * C + tq);
    const size_t Arow0 = (size_t)t * B_SZ;
    const int w = stid >> 6, lane = tid & 63;
    const int col = lane & 15, quad = lane >> 4;
    const int K = Kx;
    f32x4 acc[2][8];
#pragma unroll
    for (int mi = 0; mi < 2; ++mi)
#pragma unroll
      for (int c = 0; c < 8; ++c) acc[mi][c] = (f32x4){0.f, 0.f, 0.f, 0.f};

    const int nkb = (K + 31) / 32;
    const int rA = stid >> 1, sA = (stid & 1) * 2;
    const int nB = n0 + rA;

    uint4 va0, va1, vb0, vb1;
    {
      int k = sA * 8;
      va0 = (k < K) ? *(const uint4*)&Ax[(Arow0 + rA) * K + k] : make_uint4(0, 0, 0, 0);
      va1 = (k + 8 < K) ? *(const uint4*)&Ax[(Arow0 + rA) * K + k + 8] : make_uint4(0, 0, 0, 0);
      vb0 = (k < K && nB < 800) ? *(const uint4*)&Whx[((size_t)dir * 800 + nB) * K + k]
                                : make_uint4(0, 0, 0, 0);
      vb1 = (k + 8 < K && nB < 800) ? *(const uint4*)&Whx[((size_t)dir * 800 + nB) * K + k + 8]
                                    : make_uint4(0, 0, 0, 0);
    }

    for (int kb = 0; kb < nkb; ++kb) {
      *(uint4*)&Axs[half][rA][sA * 8] = va0;
      *(uint4*)&Axs[half][rA][sA * 8 + 8] = va1;
      *(uint4*)&Bxs[half][rA][sA * 8] = vb0;
      *(uint4*)&Bxs[half][rA][sA * 8 + 8] = vb1;
      uint4 na0 = make_uint4(0, 0, 0, 0), na1 = na0, nb0 = na0, nb1 = na0;
      if (kb + 1 < nkb) {
        int k0n = (kb + 1) * 32;
        int k = k0n + sA * 8;
        if (k < K)     na0 = *(const uint4*)&Ax[(Arow0 + rA) * K + k];
        if (k + 8 < K) na1 = *(const uint4*)&Ax[(Arow0 + rA) * K + k + 8];
        if (k < K && nB < 800)     nb0 = *(const uint4*)&Whx[((size_t)dir * 800 + nB) * K + k];
        if (k + 8 < K && nB < 800) nb1 = *(const uint4*)&Whx[((size_t)dir * 800 + nB) * K + k + 8];
      }
      asm volatile("s_waitcnt lgkmcnt(0)" ::: "memory");
      __builtin_amdgcn_s_barrier();
      __builtin_amdgcn_sched_barrier(0);
      f16x8 af0 = *(const f16x8*)&Axs[half][w * 32 + col][quad * 8];
      f16x8 af1 = *(const f16x8*)&Axs[half][w * 32 + 16 + col][quad * 8];
#pragma unroll
      for (int c = 0; c < 8; ++c) {
        f16x8 bf = *(const f16x8*)&Bxs[half][c * 16 + col][quad * 8];
        acc[0][c] = __builtin_amdgcn_mfma_f32_16x16x32_f16(af0, bf, acc[0][c], 0, 0, 0);
        acc[1][c] = __builtin_amdgcn_mfma_f32_16x16x32_f16(af1, bf, acc[1][c], 0, 0, 0);
      }
      asm volatile("s_waitcnt lgkmcnt(0)" ::: "memory");
      __builtin_amdgcn_s_barrier();
      __builtin_amdgcn_sched_barrier(0);
      va0 = na0; va1 = na1; vb0 = nb0; vb1 = nb1;
    }

#pragma unroll
    for (int c = 0; c < 8; ++c) {
      int np = n0 + c * 16 + col;
      if (np < 800) {
        float bia = bsx[dir * 800 + np];
#pragma unroll
        for (int mi = 0; mi < 2; ++mi)
#pragma unroll
          for (int r = 0; r < 4; ++r) {
            int brow = w * 32 + mi * 16 + quad * 4 + r;
            chx[(((size_t)tq * 2 + dir) * B_SZ + brow) * 800 + np] =
                __float2half(acc[mi][c][r] + bia);
          }
      }
    }
    return;
  }

  // ---------------- recurrence role ----------------
  const int wv = tid >> 6, lane = tid & 63;
  const int col = lane & 15, quad = lane >> 4;
  const int bt = blockIdx.x >> 1, d = blockIdx.x & 1;
  const int bg0 = bt * PB;

  const unsigned short* wfG = (const unsigned short*)wfragG;

  f16x8 wfrag[7][5];
#pragma unroll
  for (int u = 0; u < 7; ++u) {
    int tt = wv + 8 * u;
    int ttc = (tt < 50) ? tt : 0;
#pragma unroll
    for (int kt = 0; kt < 5; ++kt)
      wfrag[u][kt] = *(const f16x8*)&wfG[(((size_t)d * 50 + ttc) * 7 + kt) * 512 + lane * 8];
  }
  for (int idx = tid; idx < 6400; idx += 512) {
    int tt = idx >> 7, r = idx & 127;
    int kt5 = r >> 6, ln = r & 63;
    *(uint4*)&wlds[((tt << 1) + kt5) * 512 + ln * 8] =
        *(const uint4*)&wfG[(((size_t)d * 50 + tt) * 7 + 5 + kt5) * 512 + ln * 8];
  }
  for (int i = tid; i < 16 * HA_S; i += 512) {
    int m = i / HA_S, k = i - m * HA_S;
    float v = (q > 0 && m < PB && k < H_SZ)
                  ? hslab[((size_t)d * B_SZ + bg0 + m) * H_SZ + k] : 0.f;
    hA[i] = __half_as_ushort(__float2half(v));
  }
  const int p = tid;
  const int pb = p / 100, pj = (p - pb * 100) * 2;
  float2 creg = make_float2(0.f, 0.f);
  if (q > 0 && p < PB * 100)
    creg = *(const float2*)&cslab[((size_t)d * B_SZ + bg0 + pb) * H_SZ + pj];
  __syncthreads();

  uint4 cpc = make_uint4(0, 0, 0, 0);
  if (p < PB * 100)
    cpc = *(const uint4*)&chunk[((size_t)d * B_SZ + bg0 + pb) * 800 + pj * 4];

  for (int sc = 0; sc < C; ++sc) {
    const int sg = q * C + sc;
    const int t = d ? (T_SEQ - 1 - sg) : sg;

    f16x8 hf[7];
#pragma unroll
    for (int kt = 0; kt < 7; ++kt)
      hf[kt] = *(const f16x8*)&hA[col * HA_S + kt * 32 + quad * 8];

    int scn = (sc + 1 < C) ? sc + 1 : sc;
    uint4 cpn = make_uint4(0, 0, 0, 0);
    if (p < PB * 100)
      cpn = *(const uint4*)&chunk[(((size_t)scn * 2 + d) * B_SZ + bg0 + pb) * 800 + pj * 4];

#pragma unroll
    for (int u = 0; u < 7; ++u) {
      int tt = wv + 8 * u;
      if (tt < 50) {
        // split accumulator: two alternating independent chains (depth 4 & 3)
        f32x4 aA = (f32x4){0.f, 0.f, 0.f, 0.f};
        f32x4 aB = (f32x4){0.f, 0.f, 0.f, 0.f};
        f16x8 w5 = *(const f16x8*)&wlds[((tt << 1) + 0) * 512 + lane * 8];
        f16x8 w6 = *(const f16x8*)&wlds[((tt << 1) + 1) * 512 + lane * 8];
        aA = __builtin_amdgcn_mfma_f32_16x16x32_f16(wfrag[u][0], hf[0], aA, 0, 0, 0);
        aB = __builtin_amdgcn_mfma_f32_16x16x32_f16(wfrag[u][1], hf[1], aB, 0, 0, 0);
        aA = __builtin_amdgcn_mfma_f32_16x16x32_f16(wfrag[u][2], hf[2], aA, 0, 0, 0);
        aB = __builtin_amdgcn_mfma_f32_16x16x32_f16(wfrag[u][3], hf[3], aB, 0, 0, 0);
        aA = __builtin_amdgcn_mfma_f32_16x16x32_f16(wfrag[u][4], hf[4], aA, 0, 0, 0);
        aB = __builtin_amdgcn_mfma_f32_16x16x32_f16(w5, hf[5], aB, 0, 0, 0);
        aA = __builtin_amdgcn_mfma_f32_16x16x32_f16(w6, hf[6], aA, 0, 0, 0);
        if (col < PB) {
          f32x4 acc = aA + aB;
          int j = tt * 4 + quad;
          union { __half2 h2[2]; uint2 u2; } pk;
          pk.h2[0] = __floats2half2_rn(acc[0], acc[1]);
          pk.h2[1] = __floats2half2_rn(acc[2], acc[3]);
          *(uint2*)&gl[col * GL2_S + j * 4] = pk.u2;
        }
      }
    }
    asm volatile("s_waitcnt lgkmcnt(0)" ::: "memory");
    __builtin_amdgcn_s_barrier();
    __builtin_amdgcn_sched_barrier(0);

    unsigned int hstv = 0;
    if (p < PB * 100) {
      union { uint4 v; __half2 h2[4]; } G, X;
      G.v = *(const uint4*)&gl[pb * GL2_S + pj * 4];
      X.v = cpc;
      float xi0 = __low2float(X.h2[0]) + __low2float(G.h2[0]);
      float xf0 = __high2float(X.h2[0]) + __high2float(G.h2[0]);
      float xg0 = __low2float(X.h2[1]) + __low2float(G.h2[1]);
      float xo0 = __high2float(X.h2[1]) + __high2float(G.h2[1]);
      float xi1 = __low2float(X.h2[2]) + __low2float(G.h2[2]);
      float xf1 = __high2float(X.h2[2]) + __high2float(G.h2[2]);
      float xg1 = __low2float(X.h2[3]) + __low2float(G.h2[3]);
      float xo1 = __high2float(X.h2[3]) + __high2float(G.h2[3]);
      float i0 = sigf(xi0), f0 = sigf(xf0), g0 = tanf_(xg0), o0 = sigf(xo0);
      float i1 = sigf(xi1), f1 = sigf(xf1), g1 = tanf_(xg1), o1 = sigf(xo1);
      float c0 = f0 * creg.x + i0 * g0;
      float c1 = f1 * creg.y + i1 * g1;
      float h0 = o0 * tanf_(c0);
      float h1 = o1 * tanf_(c1);
      creg = make_float2(c0, c1);
      __half2 hh = __floats2half2_rn(h0, h1);
      *(__half2*)&hA[pb * HA_S + pj] = hh;
      hstv = *(unsigned int*)&hh;
    }
    asm volatile("s_waitcnt lgkmcnt(0)" ::: "memory");
    __builtin_amdgcn_s_barrier();
    __builtin_amdgcn_sched_barrier(0);
    if (p < PB * 100)
      *(unsigned int*)&hbuf[((size_t)t * B_SZ + bg0 + pb) * 400 + d * H_SZ + pj] = hstv;
    cpc = cpn;
  }

  if (p < PB * 100)
    *(float2*)&cslab[((size_t)d * B_SZ + bg0 + pb) * H_SZ + pj] = creg;
  for (int i = tid; i < PB * H_SZ; i += 512) {
    int m = i / H_SZ, k = i - m * H_SZ;
    hslab[((size_t)d * B_SZ + bg0 + m) * H_SZ + k] =
        __half2float(__ushort_as_half(hA[m * HA_S + k]));
  }
}

// emissions via MFMA: em[m][25] = h[m][400] @ lin_w[25][400]^T + lin_b
__global__ __launch_bounds__(256) void emis_mfma_kernel(const half_t* __restrict__ A,
                                                        const half_t* __restrict__ linpad,
                                                        const float* __restrict__ bias,
                                                        float* __restrict__ em) {
  const int tid = threadIdx.x;
  const int wv = tid >> 6, lane = tid & 63;
  const int col = lane & 15, quad = lane >> 4;
  const size_t m0 = (size_t)blockIdx.x * 64 + wv * 16;

  f16x8 wf[2][13];
#pragma unroll
  for (int nt = 0; nt < 2; ++nt)
#pragma unroll
    for (int kt = 0; kt < 13; ++kt)
      wf[nt][kt] = *(const f16x8*)&linpad[(nt * 16 + col) * 416 + kt * 32 + quad * 8];

  f32x4 acc[2];
  acc[0] = (f32x4){0.f, 0.f, 0.f, 0.f};
  acc[1] = (f32x4){0.f, 0.f, 0.f, 0.f};
#pragma unroll
  for (int kt = 0; kt < 13; ++kt) {
    f16x8 hfv = (f16x8)(_Float16)0.f;
    if (kt < 12 || quad < 2)
      hfv = *(const f16x8*)&A[(m0 + col) * 400 + kt * 32 + quad * 8];
    acc[0] = __builtin_amdgcn_mfma_f32_16x16x32_f16(wf[0][kt], hfv, acc[0], 0, 0, 0);
    acc[1] = __builtin_amdgcn_mfma_f32_16x16x32_f16(wf[1][kt], hfv, acc[1], 0, 0, 0);
  }
#pragma unroll
  for (int nt = 0; nt < 2; ++nt)
#pragma unroll
    for (int r = 0; r < 4; ++r) {
      int tag = nt * 16 + quad * 4 + r;
      if (tag < K_TAGS)
        em[(m0 + col) * K_TAGS + tag] = acc[nt][r] + bias[tag];
    }
}

// One wave per batch element. R14-exact crf (192 us verified): lane-pair-split
// LSE with per-step max + em prefetch. (R15 readlane: 261; R16 lagged-max: 202
// -- both reverted.)
__global__ __launch_bounds__(64) void crf_kernel(const float* __restrict__ em,
                                                 const int* __restrict__ y,
                                                 const float* __restrict__ start,
                                                 const float* __restrict__ endv,
                                                 const float* __restrict__ trans,
                                                 float* __restrict__ partial) {
  const int b = blockIdx.x;
  const int lane = threadIdx.x;
  __shared__ float tr[K_TAGS * K_TAGS];
  for (int i = lane; i < K_TAGS * K_TAGS; i += 64) tr[i] = trans[i];
  __syncthreads();

  float acc = 0.f;
  for (int t = 1 + lane; t < T_SEQ; t += 64) {
    int yp = y[b * T_SEQ + t - 1];
    int yt = y[b * T_SEQ + t];
    acc += tr[yp * K_TAGS + yt] + em[((size_t)t * B_SZ + b) * K_TAGS + yt];
  }
#pragma unroll
  for (int off = 32; off; off >>= 1) acc += __shfl_down(acc, off);
  float num = 0.f;
  if (lane == 0) {
    int y0 = y[b * T_SEQ];
    int yl = y[b * T_SEQ + T_SEQ - 1];
    num = acc + start[y0] + em[(size_t)b * K_TAGS + y0] + endv[yl];
  }

  const int jj = lane & 31;               // tag column this lane serves
  const int base = (lane & 32) ? 13 : 0;  // term range: A=[0,13), B=[13,25)
  const bool av = (jj < K_TAGS);
  float trcv[13];
#pragma unroll
  for (int i = 0; i < 13; ++i) {
    int idx = base + i;
    trcv[i] = (av && idx < K_TAGS) ? tr[idx * K_TAGS + jj] : -1e30f;
  }
  float sc = av ? start[jj] + em[(size_t)b * K_TAGS + jj] : -1e30f;

  float emt_c = av ? em[((size_t)1 * B_SZ + b) * K_TAGS + jj] : 0.f;
  for (int t = 1; t < T_SEQ; ++t) {
    float emt_n = 0.f;
    if (t + 1 < T_SEQ && av)
      emt_n = em[((size_t)(t + 1) * B_SZ + b) * K_TAGS + jj];
    float tmp[13];
#pragma unroll
    for (int i = 0; i < 13; ++i) tmp[i] = __shfl(sc, base + i) + trcv[i];
    float l1[6];
#pragma unroll
    for (int i = 0; i < 6; ++i) l1[i] = fmaxf(tmp[2 * i], tmp[2 * i + 1]);
    float l2a = fmaxf(l1[0], l1[1]), l2b = fmaxf(l1[2], l1[3]);
    float l2c = fmaxf(l1[4], l1[5]);
    float mp = fmaxf(fmaxf(l2a, l2b), fmaxf(l2c, tmp[12]));
    float m = fmaxf(mp, __shfl_xor(mp, 32));
    float e[13];
#pragma unroll
    for (int i = 0; i < 13; ++i) e[i] = __expf(tmp[i] - m);
    float s1[6];
#pragma unroll
    for (int i = 0; i < 6; ++i) s1[i] = e[2 * i] + e[2 * i + 1];
    float s2a = s1[0] + s1[1], s2b = s1[2] + s1[3], s2c = s1[4] + s1[5];
    float sp = (s2a + s2b) + (s2c + e[12]);
    float s = sp + __shfl_xor(sp, 32);
    float nv = emt_c + m + __logf(s);
    sc = av ? nv : -1e30f;
    emt_c = emt_n;
  }

  float v = (lane < K_TAGS) ? sc + endv[lane] : -1e30f;
  float m = v;
#pragma unroll
  for (int off = 32; off; off >>= 1) m = fmaxf(m, __shfl_xor(m, off));
  float s = __expf(v - m);
#pragma unroll
  for (int off = 32; off; off >>= 1) s += __shfl_xor(s, off);
  if (lane == 0) partial[b] = num - (m + __logf(s));
}

__global__ __launch_bounds__(64) void reduce_kernel(const float* __restrict__ partial,
                                                    float* __restrict__ out) {
  int lane = threadIdx.x;
  float v = partial[lane] + partial[lane + 64];
#pragma unroll
  for (int off = 32; off; off >>= 1) v += __shfl_down(v, off);
  if (lane == 0) out[0] = v;
}

extern "C" void kernel_launch(void* const* d_in, const int* in_sizes, int n_in,
                              void* d_out, int out_size, void* d_ws, size_t ws_size,
                              hipStream_t stream) {
  (void)in_sizes; (void)n_in; (void)out_size;
  const int*   x        = (const int*)d_in[0];
  const int*   y        = (const int*)d_in[1];
  const float* emb      = (const float*)d_in[3];
  const float* w_ih_l0  = (const float*)d_in[4];
  const float* w_hh_l0  = (const float*)d_in[5];
  const float* b_l0     = (const float*)d_in[6];
  const float* w_ih_l1  = (const float*)d_in[7];
  const float* w_hh_l1  = (const float*)d_in[8];
  const float* b_l1     = (const float*)d_in[9];
  const float* lin_w    = (const float*)d_in[10];
  const float* lin_b    = (const float*)d_in[11];
  const float* crf_start= (const float*)d_in[12];
  const float* crf_end  = (const float*)d_in[13];
  const float* crf_trans= (const float*)d_in[14];
  float* out = (float*)d_out;

  char* ws = (char*)d_ws;
  size_t off = 0;
  auto alloc = [&](size_t bytes) {
    size_t r = off;
    off = (off + bytes + 255) & ~(size_t)255;
    return r;
  };
  half_t* x0    = (half_t*)(ws + alloc((size_t)T_SEQ * B_SZ * K0P * 2));    // 8.4 MB
  half_t* hbuf0 = (half_t*)(ws + alloc((size_t)T_SEQ * B_SZ * 400 * 2));
  half_t* hbuf1 = (half_t*)(ws + alloc((size_t)T_SEQ * B_SZ * 400 * 2));
  float*  em    = (float*)(ws + alloc((size_t)T_SEQ * B_SZ * K_TAGS * 4));
  float*  bsum  = (float*)(ws + alloc(3200 * 4));
  half_t* wih0h = (half_t*)(ws + alloc((size_t)1600 * K0P * 2));
  half_t* wih1h = (half_t*)(ws + alloc((size_t)1600 * 400 * 2));
  half_t* wf0   = (half_t*)(ws + alloc((size_t)2 * 50 * 7 * 512 * 2));
  half_t* wf1   = (half_t*)(ws + alloc((size_t)2 * 50 * 7 * 512 * 2));
  half_t* linpad= (half_t*)(ws + alloc((size_t)32 * 416 * 2));
  float* hslab = (float*)(ws + alloc((size_t)2 * B_SZ * H_SZ * 4));
  float* cslab = (float*)(ws + alloc((size_t)2 * B_SZ * H_SZ * 4));
  float* partial = (float*)(ws + alloc(B_SZ * 4));
  size_t fixedBytes = off;

  // largest C whose DOUBLE-buffered chunk fits
  int C = 512;
  while (C > 4 && fixedBytes + (size_t)2 * C * 409600 + (1u << 20) > ws_size) C >>= 1;
  half_t* chunkA = (half_t*)(ws + alloc((size_t)2 * C * B_SZ * 800 * 2));
  half_t* chunkB = (half_t*)(ws + alloc((size_t)2 * C * B_SZ * 800 * 2));
  half_t* chbuf[2] = {chunkA, chunkB};

  embed_kernel<<<(T_SEQ * B_SZ * K0P + 255) / 256, 256, 0, stream>>>(x, emb, x0,
                                                                     b_l0, b_l1, bsum);
  conv_pad_perm_kernel<<<(1600 * K0P + 255) / 256, 256, 0, stream>>>(w_ih_l0, wih0h, D_EMB, K0P, 1600 * K0P);
  conv_pad_perm_kernel<<<(1600 * 400 + 255) / 256, 256, 0, stream>>>(w_ih_l1, wih1h, 400, 400, 1600 * 400);
  conv_pad_kernel<<<(32 * 416 + 255) / 256, 256, 0, stream>>>(lin_w, linpad, 25, 400, 416, 32 * 416);
  conv_wfrag_kernel<<<dim3((2 * 50 * 7 * 512 + 255) / 256, 2), 256, 0, stream>>>(
      w_hh_l0, w_hh_l1, wf0, wf1);

  const int nch = T_SEQ / C;
  // first chunk's xw standalone
  xw_mfma2_kernel<<<dim3(7, 2 * C), 256, 0, stream>>>(x0, wih0h, bsum, chbuf[0], K0P, C, 0);

  for (int layer = 0; layer < 2; ++layer) {
    const half_t* Wf = layer ? wf1 : wf0;
    half_t* hb = layer ? hbuf1 : hbuf0;
    for (int q = 0; q < nch; ++q) {
      int nl = layer, nq = q + 1;
      if (nq == nch) { nl = layer + 1; nq = 0; }
      int doXw = (nl < 2) ? 1 : 0;
      const half_t* Ax  = doXw ? (nl ? hbuf0 : x0) : x0;
      const half_t* Whx = doXw ? (nl ? wih1h : wih0h) : wih0h;
      const float*  bsx = doXw ? (bsum + nl * 1600) : bsum;
      half_t* chx = chbuf[nq & 1];
      int Kx = doXw ? (nl ? 400 : K0P) : K0P;
      int gridX = 128 + (doXw ? 7 * C : 0);
      persist9_kernel<<<gridX, 512, 0, stream>>>(
          chbuf[q & 1], Wf, hslab, cslab, hb, q, C,
          doXw, Ax, Whx, bsx, chx, Kx, nq);
    }
  }

  emis_mfma_kernel<<<1024, 256, 0, stream>>>(hbuf1, linpad, lin_b, em);
  crf_kernel<<<B_SZ, 64, 0, stream>>>(em, y, crf_start, crf_end, crf_trans, partial);
  reduce_kernel<<<1, 64, 0, stream>>>(partial, out);
}

// Round 18
// 1545.262 us; speedup vs baseline: 1.1316x; 1.1316x over previous
//
#include <hip/hip_runtime.h>
#include <hip/hip_fp16.h>
#include <cstddef>

using half_t = __half;
typedef __attribute__((ext_vector_type(8))) _Float16 f16x8;
typedef __attribute__((ext_vector_type(4))) float f32x4;

#define T_SEQ 512
#define B_SZ  128
#define H_SZ  200
#define D_EMB 50
#define K0P   64    // layer-0 K padded (50 -> 64)
#define K_TAGS 25
#define HA_S 232   // hA row stride (halfs)
#define GL2_S 808  // gl row stride per b (halfs)
#define PB   2     // persist b-tile rows (empirical optimum, R7 U-curve)

// Gate-interleaved weight-row permutation: n' = j*4 + gate (was n = gate*200 + j).

__device__ __forceinline__ float sigf(float x) {
  return __builtin_amdgcn_rcpf(1.f + __expf(-x));   // NaN-free at +-inf
}
__device__ __forceinline__ float tanf_(float x) {
  return 1.f - 2.f * __builtin_amdgcn_rcpf(__expf(2.f * x) + 1.f);  // NaN-free
}

// x0 strided K0P with zero pad: x0[(t*128+b)*64 + d]; bsum fused (R9).
__global__ __launch_bounds__(256) void embed_kernel(const int* __restrict__ x,
                                                    const float* __restrict__ emb,
                                                    half_t* __restrict__ x0,
                                                    const float* __restrict__ b0,
                                                    const float* __restrict__ b1,
                                                    float* __restrict__ bsum) {
  int idx = blockIdx.x * 256 + threadIdx.x;
  if (idx < 3200) {
    const float* src = (idx < 1600) ? b0 : b1;
    int Lbase = (idx < 1600) ? 0 : 1600;
    int j0 = (idx < 1600) ? idx : (idx - 1600);
    int dir = j0 / 800, n = j0 % 800;        // n = g*200 + j (original order)
    int g = n / 200, jj = n % 200;
    float v = src[dir * 1600 + n] + src[dir * 1600 + 800 + n];
    bsum[Lbase + dir * 800 + jj * 4 + g] = v;
  }
  if (idx >= T_SEQ * B_SZ * K0P) return;
  int d  = idx & (K0P - 1);
  int tb = idx >> 6;
  int b  = tb % B_SZ;
  int t  = tb / B_SZ;
  float v = 0.f;
  if (d < D_EMB) {
    int tok = x[b * T_SEQ + t];
    v = emb[(size_t)tok * D_EMB + d];
  }
  x0[idx] = __float2half(v);
}

// generic fp32->fp16 pad-convert (no permutation): dst[r][k]
__global__ __launch_bounds__(256) void conv_pad_kernel(const float* __restrict__ src,
                                                       half_t* __restrict__ dst,
                                                       int Rsrc, int Ksrc, int Kdst, int n) {
  int i = blockIdx.x * 256 + threadIdx.x;
  if (i >= n) return;
  int k = i % Kdst, r = i / Kdst;
  float v = (r < Rsrc && k < Ksrc) ? src[(size_t)r * Ksrc + k] : 0.f;
  dst[i] = __float2half(v);
}

// Wih -> fp16, rows permuted to n' = j*4+g. src [2][800][Ksrc], dst [2][800][Kdst]
__global__ __launch_bounds__(256) void conv_pad_perm_kernel(const float* __restrict__ src,
                                                            half_t* __restrict__ dst,
                                                            int Ksrc, int Kdst, int n) {
  int i = blockIdx.x * 256 + threadIdx.x;
  if (i >= n) return;
  int k   = i % Kdst;
  int np  = (i / Kdst) % 800;
  int dir = i / (Kdst * 800);
  int g = np & 3, j = np >> 2;
  float v = (k < Ksrc) ? src[((size_t)dir * 800 + g * 200 + j) * Ksrc + k] : 0.f;
  dst[i] = __float2half(v);
}

// Whh -> MFMA A-operand fragments, fp16, PERMUTED rows; both layers (R9).
__global__ __launch_bounds__(256) void conv_wfrag_kernel(const float* __restrict__ whh0,
                                                         const float* __restrict__ whh1,
                                                         half_t* __restrict__ dst0,
                                                         half_t* __restrict__ dst1) {
  int idx = blockIdx.x * 256 + threadIdx.x;
  if (idx >= 2 * 50 * 7 * 512) return;
  const float* whh = blockIdx.y ? whh1 : whh0;
  half_t* dst = blockIdx.y ? dst1 : dst0;
  int i8   = idx & 7;
  int lane = (idx >> 3) & 63;
  int kt   = (idx >> 9) % 7;
  int tmp  = (idx >> 9) / 7;      // d*50 + tt
  int tt   = tmp % 50, d = tmp / 50;
  int np = tt * 16 + (lane & 15);
  int g = np & 3, j = np >> 2;
  int k = kt * 32 + (lane >> 4) * 8 + i8;
  float v = (k < H_SZ) ? whh[((size_t)d * 800 + g * 200 + j) * H_SZ + k] : 0.f;
  dst[idx] = __float2half(v);
}

// Standalone xw GEMM (first chunk only), 128x128 tile (R8/R11 verified).
// Grid (7, 2*C), 256 thr. chunk layout (fp16): [sc][dir][b][np=800]
__global__ __launch_bounds__(256) void xw_mfma2_kernel(const half_t* __restrict__ A,
                                                       const half_t* __restrict__ Wh,
                                                       const float* __restrict__ bsumL,
                                                       half_t* __restrict__ chunk,
                                                       int K, int C, int q) {
  __shared__ __align__(16) unsigned short As[128][40];
  __shared__ __align__(16) unsigned short Bs[128][40];
  const int tid = threadIdx.x;
  const int w = tid >> 6, lane = tid & 63;
  const int col = lane & 15, quad = lane >> 4;
  const int dirTq = blockIdx.y;
  const int dir = dirTq / C;
  const int tq  = dirTq - dir * C;
  const int t = dir ? (T_SEQ - 1 - q * C - tq) : (q * C + tq);
  const int n0 = blockIdx.x * 128;
  const size_t Arow0 = (size_t)t * B_SZ;
  f32x4 acc[2][8];
#pragma unroll
  for (int mi = 0; mi < 2; ++mi)
#pragma unroll
    for (int c = 0; c < 8; ++c) acc[mi][c] = (f32x4){0.f, 0.f, 0.f, 0.f};

  const int nkb = (K + 31) / 32;
  const int rA = tid >> 1, sA = (tid & 1) * 2;
  const int nB = n0 + rA;

  uint4 va0, va1, vb0, vb1;
  {
    int k = sA * 8;
    va0 = (k < K) ? *(const uint4*)&A[(Arow0 + rA) * K + k] : make_uint4(0, 0, 0, 0);
    va1 = (k + 8 < K) ? *(const uint4*)&A[(Arow0 + rA) * K + k + 8] : make_uint4(0, 0, 0, 0);
    vb0 = (k < K && nB < 800) ? *(const uint4*)&Wh[((size_t)dir * 800 + nB) * K + k]
                              : make_uint4(0, 0, 0, 0);
    vb1 = (k + 8 < K && nB < 800) ? *(const uint4*)&Wh[((size_t)dir * 800 + nB) * K + k + 8]
                                  : make_uint4(0, 0, 0, 0);
  }

  for (int kb = 0; kb < nkb; ++kb) {
    *(uint4*)&As[rA][sA * 8] = va0;
    *(uint4*)&As[rA][sA * 8 + 8] = va1;
    *(uint4*)&Bs[rA][sA * 8] = vb0;
    *(uint4*)&Bs[rA][sA * 8 + 8] = vb1;
    uint4 na0 = make_uint4(0, 0, 0, 0), na1 = na0, nb0 = na0, nb1 = na0;
    if (kb + 1 < nkb) {
      int k0n = (kb + 1) * 32;
      int k = k0n + sA * 8;
      if (k < K)     na0 = *(const uint4*)&A[(Arow0 + rA) * K + k];
      if (k + 8 < K) na1 = *(const uint4*)&A[(Arow0 + rA) * K + k + 8];
      if (k < K && nB < 800)     nb0 = *(const uint4*)&Wh[((size_t)dir * 800 + nB) * K + k];
      if (k + 8 < K && nB < 800) nb1 = *(const uint4*)&Wh[((size_t)dir * 800 + nB) * K + k + 8];
    }
    asm volatile("s_waitcnt lgkmcnt(0)" ::: "memory");
    __builtin_amdgcn_s_barrier();
    __builtin_amdgcn_sched_barrier(0);
    f16x8 af0 = *(const f16x8*)&As[w * 32 + col][quad * 8];
    f16x8 af1 = *(const f16x8*)&As[w * 32 + 16 + col][quad * 8];
#pragma unroll
    for (int c = 0; c < 8; ++c) {
      f16x8 bf = *(const f16x8*)&Bs[c * 16 + col][quad * 8];
      acc[0][c] = __builtin_amdgcn_mfma_f32_16x16x32_f16(af0, bf, acc[0][c], 0, 0, 0);
      acc[1][c] = __builtin_amdgcn_mfma_f32_16x16x32_f16(af1, bf, acc[1][c], 0, 0, 0);
    }
    asm volatile("s_waitcnt lgkmcnt(0)" ::: "memory");
    __builtin_amdgcn_s_barrier();
    __builtin_amdgcn_sched_barrier(0);
    va0 = na0; va1 = na1; vb0 = nb0; vb1 = nb1;
  }

#pragma unroll
  for (int c = 0; c < 8; ++c) {
    int np = n0 + c * 16 + col;
    if (np < 800) {
      float bia = bsumL[dir * 800 + np];
#pragma unroll
      for (int mi = 0; mi < 2; ++mi)
#pragma unroll
        for (int r = 0; r < 4; ++r) {
          int brow = w * 32 + mi * 16 + quad * 4 + r;
          chunk[(((size_t)tq * 2 + dir) * B_SZ + brow) * 800 + np] =
              __float2half(acc[mi][c][r] + bia);
        }
    }
  }
}

// R13 FUSED kernel: blocks 0..127 = persist5 recurrence (R14-exact, verified);
// blocks 128.. = xw GEMM for the NEXT chunk. (R17 split-acc reverted: regressed.)
__global__ __launch_bounds__(512)
__attribute__((amdgpu_waves_per_eu(2, 2)))
void persist9_kernel(
    const half_t* __restrict__ chunk,     // rec: [sc][d][b][np] fp16
    const half_t* __restrict__ wfragG,    // [d][50][7][64][8] fp16 (permuted)
    float* __restrict__ hslab,            // [d][128][200] fp32
    float* __restrict__ cslab,            // [d][128][200] fp32
    half_t* __restrict__ hbuf,            // [t][128][400] fp16
    int q, int C,
    int doXw,
    const half_t* __restrict__ Ax,        // xw: activation input
    const half_t* __restrict__ Whx,       // xw: weights (permuted rows)
    const float* __restrict__ bsx,        // xw: bias
    half_t* __restrict__ chx,             // xw: output chunk (other buffer)
    int Kx, int qx) {
  const int tid = threadIdx.x;

  __shared__ __align__(16) unsigned short wlds[50 * 2 * 512];  // 102400 B
  __shared__ __align__(16) unsigned short gl[PB * GL2_S];      // 3232 B
  __shared__ __align__(16) unsigned short hA[16 * HA_S];       // 7424 B
  __shared__ __align__(16) unsigned short Axs[2][128][40];     // 20480 B
  __shared__ __align__(16) unsigned short Bxs[2][128][40];     // 20480 B

  if (blockIdx.x >= 128) {
    // ---------------- xw role (next chunk) ----------------
    const int xb = blockIdx.x - 128;
    const int n0 = (xb % 7) * 128;
    const int pair = xb / 7;             // [0, C)
    const int half = tid >> 8;           // wave-uniform (256 | wave bounds)
    const int stid = tid & 255;
    const int dir = half, tq = pair;
    const int t = dir ? (T_SEQ - 1 - qx * C - tq) : (qx * C + tq);
    const size_t Arow0 = (size_t)t * B_SZ;
    const int w = stid >> 6, lane = tid & 63;
    const int col = lane & 15, quad = lane >> 4;
    const int K = Kx;
    f32x4 acc[2][8];
#pragma unroll
    for (int mi = 0; mi < 2; ++mi)
#pragma unroll
      for (int c = 0; c < 8; ++c) acc[mi][c] = (f32x4){0.f, 0.f, 0.f, 0.f};

    const int nkb = (K + 31) / 32;
    const int rA = stid >> 1, sA = (stid & 1) * 2;
    const int nB = n0 + rA;

    uint4 va0, va1, vb0, vb1;
    {
      int k = sA * 8;
      va0 = (k < K) ? *(const uint4*)&Ax[(Arow0 + rA) * K + k] : make_uint4(0, 0, 0, 0);
      va1 = (k + 8 < K) ? *(const uint4*)&Ax[(Arow0 + rA) * K + k + 8] : make_uint4(0, 0, 0, 0);
      vb0 = (k < K && nB < 800) ? *(const uint4*)&Whx[((size_t)dir * 800 + nB) * K + k]
                                : make_uint4(0, 0, 0, 0);
      vb1 = (k + 8 < K && nB < 800) ? *(const uint4*)&Whx[((size_t)dir * 800 + nB) * K + k + 8]
                                    : make_uint4(0, 0, 0, 0);
    }

    for (int kb = 0; kb < nkb; ++kb) {
      *(uint4*)&Axs[half][rA][sA * 8] = va0;
      *(uint4*)&Axs[half][rA][sA * 8 + 8] = va1;
      *(uint4*)&Bxs[half][rA][sA * 8] = vb0;
      *(uint4*)&Bxs[half][rA][sA * 8 + 8] = vb1;
      uint4 na0 = make_uint4(0, 0, 0, 0), na1 = na0, nb0 = na0, nb1 = na0;
      if (kb + 1 < nkb) {
        int k0n = (kb + 1) * 32;
        int k = k0n + sA * 8;
        if (k < K)     na0 = *(const uint4*)&Ax[(Arow0 + rA) * K + k];
        if (k + 8 < K) na1 = *(const uint4*)&Ax[(Arow0 + rA) * K + k + 8];
        if (k < K && nB < 800)     nb0 = *(const uint4*)&Whx[((size_t)dir * 800 + nB) * K + k];
        if (k + 8 < K && nB < 800) nb1 = *(const uint4*)&Whx[((size_t)dir * 800 + nB) * K + k + 8];
      }
      asm volatile("s_waitcnt lgkmcnt(0)" ::: "memory");
      __builtin_amdgcn_s_barrier();
      __builtin_amdgcn_sched_barrier(0);
      f16x8 af0 = *(const f16x8*)&Axs[half][w * 32 + col][quad * 8];
      f16x8 af1 = *(const f16x8*)&Axs[half][w * 32 + 16 + col][quad * 8];
#pragma unroll
      for (int c = 0; c < 8; ++c) {
        f16x8 bf = *(const f16x8*)&Bxs[half][c * 16 + col][quad * 8];
        acc[0][c] = __builtin_amdgcn_mfma_f32_16x16x32_f16(af0, bf, acc[0][c], 0, 0, 0);
        acc[1][c] = __builtin_amdgcn_mfma_f32_16x16x32_f16(af1, bf, acc[1][c], 0, 0, 0);
      }
      asm volatile("s_waitcnt lgkmcnt(0)" ::: "memory");
      __builtin_amdgcn_s_barrier();
      __builtin_amdgcn_sched_barrier(0);
      va0 = na0; va1 = na1; vb0 = nb0; vb1 = nb1;
    }

#pragma unroll
    for (int c = 0; c < 8; ++c) {
      int np = n0 + c * 16 + col;
      if (np < 800) {
        float bia = bsx[dir * 800 + np];
#pragma unroll
        for (int mi = 0; mi < 2; ++mi)
#pragma unroll
          for (int r = 0; r < 4; ++r) {
            int brow = w * 32 + mi * 16 + quad * 4 + r;
            chx[(((size_t)tq * 2 + dir) * B_SZ + brow) * 800 + np] =
                __float2half(acc[mi][c][r] + bia);
          }
      }
    }
    return;
  }

  // ---------------- recurrence role (persist5, R14-exact) ----------------
  const int wv = tid >> 6, lane = tid & 63;
  const int col = lane & 15, quad = lane >> 4;
  const int bt = blockIdx.x >> 1, d = blockIdx.x & 1;
  const int bg0 = bt * PB;

  const unsigned short* wfG = (const unsigned short*)wfragG;

  f16x8 wfrag[7][5];
#pragma unroll
  for (int u = 0; u < 7; ++u) {
    int tt = wv + 8 * u;
    int ttc = (tt < 50) ? tt : 0;
#pragma unroll
    for (int kt = 0; kt < 5; ++kt)
      wfrag[u][kt] = *(const f16x8*)&wfG[(((size_t)d * 50 + ttc) * 7 + kt) * 512 + lane * 8];
  }
  for (int idx = tid; idx < 6400; idx += 512) {
    int tt = idx >> 7, r = idx & 127;
    int kt5 = r >> 6, ln = r & 63;
    *(uint4*)&wlds[((tt << 1) + kt5) * 512 + ln * 8] =
        *(const uint4*)&wfG[(((size_t)d * 50 + tt) * 7 + 5 + kt5) * 512 + ln * 8];
  }
  for (int i = tid; i < 16 * HA_S; i += 512) {
    int m = i / HA_S, k = i - m * HA_S;
    float v = (q > 0 && m < PB && k < H_SZ)
                  ? hslab[((size_t)d * B_SZ + bg0 + m) * H_SZ + k] : 0.f;
    hA[i] = __half_as_ushort(__float2half(v));
  }
  const int p = tid;
  const int pb = p / 100, pj = (p - pb * 100) * 2;
  float2 creg = make_float2(0.f, 0.f);
  if (q > 0 && p < PB * 100)
    creg = *(const float2*)&cslab[((size_t)d * B_SZ + bg0 + pb) * H_SZ + pj];
  __syncthreads();

  uint4 cpc = make_uint4(0, 0, 0, 0);
  if (p < PB * 100)
    cpc = *(const uint4*)&chunk[((size_t)d * B_SZ + bg0 + pb) * 800 + pj * 4];

  for (int sc = 0; sc < C; ++sc) {
    const int sg = q * C + sc;
    const int t = d ? (T_SEQ - 1 - sg) : sg;

    f16x8 hf[7];
#pragma unroll
    for (int kt = 0; kt < 7; ++kt)
      hf[kt] = *(const f16x8*)&hA[col * HA_S + kt * 32 + quad * 8];

    int scn = (sc + 1 < C) ? sc + 1 : sc;
    uint4 cpn = make_uint4(0, 0, 0, 0);
    if (p < PB * 100)
      cpn = *(const uint4*)&chunk[(((size_t)scn * 2 + d) * B_SZ + bg0 + pb) * 800 + pj * 4];

#pragma unroll
    for (int u = 0; u < 7; ++u) {
      int tt = wv + 8 * u;
      if (tt < 50) {
        f32x4 acc = (f32x4){0.f, 0.f, 0.f, 0.f};
#pragma unroll
        for (int kt = 0; kt < 7; ++kt) {
          f16x8 wf = (kt < 5) ? wfrag[u][kt]
                              : *(const f16x8*)&wlds[((tt << 1) + (kt - 5)) * 512 + lane * 8];
          acc = __builtin_amdgcn_mfma_f32_16x16x32_f16(wf, hf[kt], acc, 0, 0, 0);
        }
        if (col < PB) {
          int j = tt * 4 + quad;
          union { __half2 h2[2]; uint2 u2; } pk;
          pk.h2[0] = __floats2half2_rn(acc[0], acc[1]);
          pk.h2[1] = __floats2half2_rn(acc[2], acc[3]);
          *(uint2*)&gl[col * GL2_S + j * 4] = pk.u2;
        }
      }
    }
    asm volatile("s_waitcnt lgkmcnt(0)" ::: "memory");
    __builtin_amdgcn_s_barrier();
    __builtin_amdgcn_sched_barrier(0);

    unsigned int hstv = 0;
    if (p < PB * 100) {
      union { uint4 v; __half2 h2[4]; } G, X;
      G.v = *(const uint4*)&gl[pb * GL2_S + pj * 4];
      X.v = cpc;
      float xi0 = __low2float(X.h2[0]) + __low2float(G.h2[0]);
      float xf0 = __high2float(X.h2[0]) + __high2float(G.h2[0]);
      float xg0 = __low2float(X.h2[1]) + __low2float(G.h2[1]);
      float xo0 = __high2float(X.h2[1]) + __high2float(G.h2[1]);
      float xi1 = __low2float(X.h2[2]) + __low2float(G.h2[2]);
      float xf1 = __high2float(X.h2[2]) + __high2float(G.h2[2]);
      float xg1 = __low2float(X.h2[3]) + __low2float(G.h2[3]);
      float xo1 = __high2float(X.h2[3]) + __high2float(G.h2[3]);
      float i0 = sigf(xi0), f0 = sigf(xf0), g0 = tanf_(xg0), o0 = sigf(xo0);
      float i1 = sigf(xi1), f1 = sigf(xf1), g1 = tanf_(xg1), o1 = sigf(xo1);
      float c0 = f0 * creg.x + i0 * g0;
      float c1 = f1 * creg.y + i1 * g1;
      float h0 = o0 * tanf_(c0);
      float h1 = o1 * tanf_(c1);
      creg = make_float2(c0, c1);
      __half2 hh = __floats2half2_rn(h0, h1);
      *(__half2*)&hA[pb * HA_S + pj] = hh;
      hstv = *(unsigned int*)&hh;
    }
    asm volatile("s_waitcnt lgkmcnt(0)" ::: "memory");
    __builtin_amdgcn_s_barrier();
    __builtin_amdgcn_sched_barrier(0);
    if (p < PB * 100)
      *(unsigned int*)&hbuf[((size_t)t * B_SZ + bg0 + pb) * 400 + d * H_SZ + pj] = hstv;
    cpc = cpn;
  }

  if (p < PB * 100)
    *(float2*)&cslab[((size_t)d * B_SZ + bg0 + pb) * H_SZ + pj] = creg;
  for (int i = tid; i < PB * H_SZ; i += 512) {
    int m = i / H_SZ, k = i - m * H_SZ;
    hslab[((size_t)d * B_SZ + bg0 + m) * H_SZ + k] =
        __half2float(__ushort_as_half(hA[m * HA_S + k]));
  }
}

// emissions via MFMA: em[m][25] = h[m][400] @ lin_w[25][400]^T + lin_b
__global__ __launch_bounds__(256) void emis_mfma_kernel(const half_t* __restrict__ A,
                                                        const half_t* __restrict__ linpad,
                                                        const float* __restrict__ bias,
                                                        float* __restrict__ em) {
  const int tid = threadIdx.x;
  const int wv = tid >> 6, lane = tid & 63;
  const int col = lane & 15, quad = lane >> 4;
  const size_t m0 = (size_t)blockIdx.x * 64 + wv * 16;

  f16x8 wf[2][13];
#pragma unroll
  for (int nt = 0; nt < 2; ++nt)
#pragma unroll
    for (int kt = 0; kt < 13; ++kt)
      wf[nt][kt] = *(const f16x8*)&linpad[(nt * 16 + col) * 416 + kt * 32 + quad * 8];

  f32x4 acc[2];
  acc[0] = (f32x4){0.f, 0.f, 0.f, 0.f};
  acc[1] = (f32x4){0.f, 0.f, 0.f, 0.f};
#pragma unroll
  for (int kt = 0; kt < 13; ++kt) {
    f16x8 hfv = (f16x8)(_Float16)0.f;
    if (kt < 12 || quad < 2)
      hfv = *(const f16x8*)&A[(m0 + col) * 400 + kt * 32 + quad * 8];
    acc[0] = __builtin_amdgcn_mfma_f32_16x16x32_f16(wf[0][kt], hfv, acc[0], 0, 0, 0);
    acc[1] = __builtin_amdgcn_mfma_f32_16x16x32_f16(wf[1][kt], hfv, acc[1], 0, 0, 0);
  }
#pragma unroll
  for (int nt = 0; nt < 2; ++nt)
#pragma unroll
    for (int r = 0; r < 4; ++r) {
      int tag = nt * 16 + quad * 4 + r;
      if (tag < K_TAGS)
        em[(m0 + col) * K_TAGS + tag] = acc[nt][r] + bias[tag];
    }
}

// R18: SPLIT forward/backward CRF. logZ = LSE_j(alpha_t(j)+beta_t(j)) at any
// cut t, so wave 0 runs the forward scan on [0,255] while wave 1 runs the
// backward scan on [511,255] CONCURRENTLY -- serial chain 511 -> 256 steps.
// Both use the R14-verified pair-split LSE body (192us/511step): forward uses
// trans COLUMNS, backward uses trans ROWS with em folded into the shuffled
// operand. Combine via LDS. 128 thr/block.
__global__ __launch_bounds__(128) void crf_kernel(const float* __restrict__ em,
                                                 const int* __restrict__ y,
                                                 const float* __restrict__ start,
                                                 const float* __restrict__ endv,
                                                 const float* __restrict__ trans,
                                                 float* __restrict__ partial) {
  const int b = blockIdx.x;
  const int tid = threadIdx.x;
  const int wvi = tid >> 6, lane = tid & 63;
  __shared__ float tr[K_TAGS * K_TAGS];
  __shared__ float aL[K_TAGS], bL[K_TAGS];
  for (int i = tid; i < K_TAGS * K_TAGS; i += 128) tr[i] = trans[i];
  __syncthreads();

  const int jj = lane & 31;               // tag index this lane serves
  const int base = (lane & 32) ? 13 : 0;  // term range: A=[0,13), B=[13,25)
  const bool av = (jj < K_TAGS);

  float num = 0.f;
  if (wvi == 0) {
    // ---- gold-path score + forward scan t = 1..255 ----
    float acc = 0.f;
    for (int t = 1 + lane; t < T_SEQ; t += 64) {
      int yp = y[b * T_SEQ + t - 1];
      int yt = y[b * T_SEQ + t];
      acc += tr[yp * K_TAGS + yt] + em[((size_t)t * B_SZ + b) * K_TAGS + yt];
    }
#pragma unroll
    for (int off = 32; off; off >>= 1) acc += __shfl_down(acc, off);
    if (lane == 0) {
      int y0 = y[b * T_SEQ];
      int yl = y[b * T_SEQ + T_SEQ - 1];
      num = acc + start[y0] + em[(size_t)b * K_TAGS + y0] + endv[yl];
    }

    float trcv[13];   // column slice: tr[(base+i)][jj]
#pragma unroll
    for (int i = 0; i < 13; ++i) {
      int idx = base + i;
      trcv[i] = (av && idx < K_TAGS) ? tr[idx * K_TAGS + jj] : -1e30f;
    }
    float sc = av ? start[jj] + em[(size_t)b * K_TAGS + jj] : -1e30f;
    float emt_c = av ? em[((size_t)1 * B_SZ + b) * K_TAGS + jj] : 0.f;
    for (int t = 1; t <= 255; ++t) {
      float emt_n = 0.f;
      if (t < 255 && av)
        emt_n = em[((size_t)(t + 1) * B_SZ + b) * K_TAGS + jj];
      float tmp[13];
#pragma unroll
      for (int i = 0; i < 13; ++i) tmp[i] = __shfl(sc, base + i) + trcv[i];
      float l1[6];
#pragma unroll
      for (int i = 0; i < 6; ++i) l1[i] = fmaxf(tmp[2 * i], tmp[2 * i + 1]);
      float l2a = fmaxf(l1[0], l1[1]), l2b = fmaxf(l1[2], l1[3]);
      float l2c = fmaxf(l1[4], l1[5]);
      float mp = fmaxf(fmaxf(l2a, l2b), fmaxf(l2c, tmp[12]));
      float m = fmaxf(mp, __shfl_xor(mp, 32));
      float e[13];
#pragma unroll
      for (int i = 0; i < 13; ++i) e[i] = __expf(tmp[i] - m);
      float s1[6];
#pragma unroll
      for (int i = 0; i < 6; ++i) s1[i] = e[2 * i] + e[2 * i + 1];
      float s2a = s1[0] + s1[1], s2b = s1[2] + s1[3], s2c = s1[4] + s1[5];
      float sp = (s2a + s2b) + (s2c + e[12]);
      float s = sp + __shfl_xor(sp, 32);
      float nv = emt_c + m + __logf(s);
      sc = av ? nv : -1e30f;
      emt_c = emt_n;
    }
    if (lane < K_TAGS) aL[lane] = sc;      // alpha_255 (lanes 0..24 valid)
  } else {
    // ---- backward scan t = 510..255: beta_t(i)=LSE_j(tr[i][j]+em_{t+1}(j)+beta_{t+1}(j)) ----
    float trow[13];   // row slice: tr[jj][base+i]
#pragma unroll
    for (int i = 0; i < 13; ++i) {
      int idx = base + i;
      trow[i] = (av && idx < K_TAGS) ? tr[jj * K_TAGS + idx] : -1e30f;
    }
    float beta = av ? endv[jj] : -1e30f;   // beta_511
    float w = av ? beta + em[((size_t)511 * B_SZ + b) * K_TAGS + jj] : -1e30f;
    float emt_c = av ? em[((size_t)510 * B_SZ + b) * K_TAGS + jj] : 0.f;
    for (int t = 510; t >= 255; --t) {
      float emt_n = 0.f;
      if (t > 255 && av)
        emt_n = em[((size_t)(t - 1) * B_SZ + b) * K_TAGS + jj];
      float tmp[13];
#pragma unroll
      for (int i = 0; i < 13; ++i) tmp[i] = __shfl(w, base + i) + trow[i];
      float l1[6];
#pragma unroll
      for (int i = 0; i < 6; ++i) l1[i] = fmaxf(tmp[2 * i], tmp[2 * i + 1]);
      float l2a = fmaxf(l1[0], l1[1]), l2b = fmaxf(l1[2], l1[3]);
      float l2c = fmaxf(l1[4], l1[5]);
      float mp = fmaxf(fmaxf(l2a, l2b), fmaxf(l2c, tmp[12]));
      float m = fmaxf(mp, __shfl_xor(mp, 32));
      float e[13];
#pragma unroll
      for (int i = 0; i < 13; ++i) e[i] = __expf(tmp[i] - m);
      float s1[6];
#pragma unroll
      for (int i = 0; i < 6; ++i) s1[i] = e[2 * i] + e[2 * i + 1];
      float s2a = s1[0] + s1[1], s2b = s1[2] + s1[3], s2c = s1[4] + s1[5];
      float sp = (s2a + s2b) + (s2c + e[12]);
      float s = sp + __shfl_xor(sp, 32);
      float bt = m + __logf(s);
      beta = av ? bt : -1e30f;
      w = av ? bt + emt_c : -1e30f;
      emt_c = emt_n;
    }
    if (lane < K_TAGS) bL[lane] = beta;    // beta_255
  }
  __syncthreads();
  if (wvi == 0) {
    float v = (lane < K_TAGS) ? aL[lane] + bL[lane] : -1e30f;
    float m = v;
#pragma unroll
    for (int off = 32; off; off >>= 1) m = fmaxf(m, __shfl_xor(m, off));
    float s = __expf(v - m);
#pragma unroll
    for (int off = 32; off; off >>= 1) s += __shfl_xor(s, off);
    if (lane == 0) partial[b] = num - (m + __logf(s));
  }
}

__global__ __launch_bounds__(64) void reduce_kernel(const float* __restrict__ partial,
                                                    float* __restrict__ out) {
  int lane = threadIdx.x;
  float v = partial[lane] + partial[lane + 64];
#pragma unroll
  for (int off = 32; off; off >>= 1) v += __shfl_down(v, off);
  if (lane == 0) out[0] = v;
}

extern "C" void kernel_launch(void* const* d_in, const int* in_sizes, int n_in,
                              void* d_out, int out_size, void* d_ws, size_t ws_size,
                              hipStream_t stream) {
  (void)in_sizes; (void)n_in; (void)out_size;
  const int*   x        = (const int*)d_in[0];
  const int*   y        = (const int*)d_in[1];
  const float* emb      = (const float*)d_in[3];
  const float* w_ih_l0  = (const float*)d_in[4];
  const float* w_hh_l0  = (const float*)d_in[5];
  const float* b_l0     = (const float*)d_in[6];
  const float* w_ih_l1  = (const float*)d_in[7];
  const float* w_hh_l1  = (const float*)d_in[8];
  const float* b_l1     = (const float*)d_in[9];
  const float* lin_w    = (const float*)d_in[10];
  const float* lin_b    = (const float*)d_in[11];
  const float* crf_start= (const float*)d_in[12];
  const float* crf_end  = (const float*)d_in[13];
  const float* crf_trans= (const float*)d_in[14];
  float* out = (float*)d_out;

  char* ws = (char*)d_ws;
  size_t off = 0;
  auto alloc = [&](size_t bytes) {
    size_t r = off;
    off = (off + bytes + 255) & ~(size_t)255;
    return r;
  };
  half_t* x0    = (half_t*)(ws + alloc((size_t)T_SEQ * B_SZ * K0P * 2));    // 8.4 MB
  half_t* hbuf0 = (half_t*)(ws + alloc((size_t)T_SEQ * B_SZ * 400 * 2));
  half_t* hbuf1 = (half_t*)(ws + alloc((size_t)T_SEQ * B_SZ * 400 * 2));
  float*  em    = (float*)(ws + alloc((size_t)T_SEQ * B_SZ * K_TAGS * 4));
  float*  bsum  = (float*)(ws + alloc(3200 * 4));
  half_t* wih0h = (half_t*)(ws + alloc((size_t)1600 * K0P * 2));
  half_t* wih1h = (half_t*)(ws + alloc((size_t)1600 * 400 * 2));
  half_t* wf0   = (half_t*)(ws + alloc((size_t)2 * 50 * 7 * 512 * 2));
  half_t* wf1   = (half_t*)(ws + alloc((size_t)2 * 50 * 7 * 512 * 2));
  half_t* linpad= (half_t*)(ws + alloc((size_t)32 * 416 * 2));
  float* hslab = (float*)(ws + alloc((size_t)2 * B_SZ * H_SZ * 4));
  float* cslab = (float*)(ws + alloc((size_t)2 * B_SZ * H_SZ * 4));
  float* partial = (float*)(ws + alloc(B_SZ * 4));
  size_t fixedBytes = off;

  // largest C whose DOUBLE-buffered chunk fits
  int C = 512;
  while (C > 4 && fixedBytes + (size_t)2 * C * 409600 + (1u << 20) > ws_size) C >>= 1;
  half_t* chunkA = (half_t*)(ws + alloc((size_t)2 * C * B_SZ * 800 * 2));
  half_t* chunkB = (half_t*)(ws + alloc((size_t)2 * C * B_SZ * 800 * 2));
  half_t* chbuf[2] = {chunkA, chunkB};

  embed_kernel<<<(T_SEQ * B_SZ * K0P + 255) / 256, 256, 0, stream>>>(x, emb, x0,
                                                                     b_l0, b_l1, bsum);
  conv_pad_perm_kernel<<<(1600 * K0P + 255) / 256, 256, 0, stream>>>(w_ih_l0, wih0h, D_EMB, K0P, 1600 * K0P);
  conv_pad_perm_kernel<<<(1600 * 400 + 255) / 256, 256, 0, stream>>>(w_ih_l1, wih1h, 400, 400, 1600 * 400);
  conv_pad_kernel<<<(32 * 416 + 255) / 256, 256, 0, stream>>>(lin_w, linpad, 25, 400, 416, 32 * 416);
  conv_wfrag_kernel<<<dim3((2 * 50 * 7 * 512 + 255) / 256, 2), 256, 0, stream>>>(
      w_hh_l0, w_hh_l1, wf0, wf1);

  const int nch = T_SEQ / C;
  // first chunk's xw standalone
  xw_mfma2_kernel<<<dim3(7, 2 * C), 256, 0, stream>>>(x0, wih0h, bsum, chbuf[0], K0P, C, 0);

  for (int layer = 0; layer < 2; ++layer) {
    const half_t* Wf = layer ? wf1 : wf0;
    half_t* hb = layer ? hbuf1 : hbuf0;
    for (int q = 0; q < nch; ++q) {
      int nl = layer, nq = q + 1;
      if (nq == nch) { nl = layer + 1; nq = 0; }
      int doXw = (nl < 2) ? 1 : 0;
      const half_t* Ax  = doXw ? (nl ? hbuf0 : x0) : x0;
      const half_t* Whx = doXw ? (nl ? wih1h : wih0h) : wih0h;
      const float*  bsx = doXw ? (bsum + nl * 1600) : bsum;
      half_t* chx = chbuf[nq & 1];
      int Kx = doXw ? (nl ? 400 : K0P) : K0P;
      int gridX = 128 + (doXw ? 7 * C : 0);
      persist9_kernel<<<gridX, 512, 0, stream>>>(
          chbuf[q & 1], Wf, hslab, cslab, hb, q, C,
          doXw, Ax, Whx, bsx, chx, Kx, nq);
    }
  }

  emis_mfma_kernel<<<1024, 256, 0, stream>>>(hbuf1, linpad, lin_b, em);
  crf_kernel<<<B_SZ, 128, 0, stream>>>(em, y, crf_start, crf_end, crf_trans, partial);
  reduce_kernel<<<1, 64, 0, stream>>>(partial, out);
}